// Round 3
// baseline (25983.008 us; speedup 1.0000x reference)
//
#include <hip/hip_runtime.h>

#define EPS   1e-5f
#define SLOPE 0.01f

// ---------------------------------------------------------------------------
// conv 3x3x3 pad=1 (cross-correlation), cout-register-blocked + ci-split.
// in: [CIN][D][H][W], wt: [Cout][CIN][3][3][3]
// grid: (V/(256*VOXB), Cout/COB, CIN/CC). Block z handles ci chunk [z*CC, z*CC+CC).
// Writes partial sums to part[z][co][v] (reduced later inside the BN kernels).
// ---------------------------------------------------------------------------
template <int CIN, int CC, int COB, int VOXB>
__global__ __launch_bounds__(256) void conv3_v4(const float* __restrict__ in,
                                                const float* __restrict__ wt,
                                                float* __restrict__ part,
                                                int D, int H, int W) {
    const int V    = D * H * W;
    const int Cout = gridDim.y * COB;
    const int z    = blockIdx.z;
    const int cib  = z * CC;
    __shared__ float wlds[27 * CC * COB];
    const int co0 = blockIdx.y * COB;
    for (int i = threadIdx.x; i < 27 * CC * COB; i += 256) {
        const int tap = i / (CC * COB);
        const int r   = i - tap * (CC * COB);
        const int ci  = r / COB;
        const int co  = r - ci * COB;
        wlds[i] = wt[((size_t)(co0 + co) * CIN + cib + ci) * 27 + tap];
    }
    __syncthreads();

    const float* inz = in + (size_t)cib * V;
    const int vbase = blockIdx.x * (256 * VOXB) + threadIdx.x;
    int dd[VOXB], hh[VOXB], ww[VOXB];
#pragma unroll
    for (int j = 0; j < VOXB; ++j) {
        const int v = vbase + j * 256;
        ww[j] = v % W;
        hh[j] = (v / W) % H;
        dd[j] = v / (W * H);
    }
    float acc[COB * VOXB];
#pragma unroll
    for (int i = 0; i < COB * VOXB; ++i) acc[i] = 0.f;

    constexpr int UNR = (CC * VOXB <= 32) ? CC : (32 / VOXB);

#pragma unroll
    for (int kd = 0; kd < 3; ++kd)
#pragma unroll
    for (int kh = 0; kh < 3; ++kh)
#pragma unroll
    for (int kw = 0; kw < 3; ++kw) {
        const int tap = (kd * 3 + kh) * 3 + kw;
        int sp[VOXB]; bool ok[VOXB];
#pragma unroll
        for (int j = 0; j < VOXB; ++j) {
            const int zd = dd[j] + kd - 1, zh = hh[j] + kh - 1, zw = ww[j] + kw - 1;
            ok[j] = ((unsigned)zd < (unsigned)D) & ((unsigned)zh < (unsigned)H) &
                    ((unsigned)zw < (unsigned)W);
            sp[j] = (zd * H + zh) * W + zw;
        }
        const float* wrow = &wlds[tap * CC * COB];
        for (int ci0 = 0; ci0 < CC; ci0 += UNR) {
            float xv[UNR * VOXB];
#pragma unroll
            for (int u = 0; u < UNR; ++u)
#pragma unroll
                for (int j = 0; j < VOXB; ++j)
                    xv[u * VOXB + j] = ok[j] ? inz[(size_t)(ci0 + u) * V + sp[j]] : 0.f;
#pragma unroll
            for (int u = 0; u < UNR; ++u) {
                const float* wp = wrow + (ci0 + u) * COB;
#pragma unroll
                for (int co = 0; co < COB; ++co) {
                    const float wgt = wp[co];
#pragma unroll
                    for (int j = 0; j < VOXB; ++j)
                        acc[co * VOXB + j] = fmaf(xv[u * VOXB + j], wgt, acc[co * VOXB + j]);
                }
            }
        }
    }
#pragma unroll
    for (int co = 0; co < COB; ++co)
#pragma unroll
        for (int j = 0; j < VOXB; ++j)
            part[((size_t)z * Cout + co0 + co) * V + vbase + j * 256] = acc[co * VOXB + j];
}

// ---------------------------------------------------------------------------
// upconv (NN-upsample x2 + circular 2x2x2 true convolution), cout-blocked + ci-split
// ---------------------------------------------------------------------------
template <int CIN, int CC, int COB, int VOXB>
__global__ __launch_bounds__(256) void upconv_v4(const float* __restrict__ in,
                                                 const float* __restrict__ wt,
                                                 float* __restrict__ part,
                                                 int Di, int Hi, int Wi) {
    const int Do = 2 * Di, Ho = 2 * Hi, Wo = 2 * Wi;
    const int Vo = Do * Ho * Wo;
    const int Vi = Di * Hi * Wi;
    const int Cout = gridDim.y * COB;
    const int z   = blockIdx.z;
    const int cib = z * CC;
    __shared__ float wlds[8 * CC * COB];
    const int co0 = blockIdx.y * COB;
    for (int i = threadIdx.x; i < 8 * CC * COB; i += 256) {
        const int tap = i / (CC * COB);
        const int r   = i - tap * (CC * COB);
        const int ci  = r / COB;
        const int co  = r - ci * COB;
        wlds[i] = wt[((size_t)(co0 + co) * CIN + cib + ci) * 8 + tap];
    }
    __syncthreads();

    const float* inz = in + (size_t)cib * Vi;
    const int vbase = blockIdx.x * (256 * VOXB) + threadIdx.x;
    int od[VOXB], oh[VOXB], ow[VOXB];
#pragma unroll
    for (int j = 0; j < VOXB; ++j) {
        const int v = vbase + j * 256;
        ow[j] = v % Wo;
        oh[j] = (v / Wo) % Ho;
        od[j] = v / (Wo * Ho);
    }
    float acc[COB * VOXB];
#pragma unroll
    for (int i = 0; i < COB * VOXB; ++i) acc[i] = 0.f;

    constexpr int UNR = (CC * VOXB <= 32) ? CC : (32 / VOXB);

#pragma unroll
    for (int kd = 0; kd < 2; ++kd)
#pragma unroll
    for (int kh = 0; kh < 2; ++kh)
#pragma unroll
    for (int kw = 0; kw < 2; ++kw) {
        const int tap = (kd * 2 + kh) * 2 + kw;
        int sp[VOXB];
#pragma unroll
        for (int j = 0; j < VOXB; ++j) {
            const int id = ((od[j] - kd + Do) & (Do - 1)) >> 1;
            const int ih = ((oh[j] - kh + Ho) & (Ho - 1)) >> 1;
            const int iw = ((ow[j] - kw + Wo) & (Wo - 1)) >> 1;
            sp[j] = (id * Hi + ih) * Wi + iw;
        }
        const float* wrow = &wlds[tap * CC * COB];
        for (int ci0 = 0; ci0 < CC; ci0 += UNR) {
            float xv[UNR * VOXB];
#pragma unroll
            for (int u = 0; u < UNR; ++u)
#pragma unroll
                for (int j = 0; j < VOXB; ++j)
                    xv[u * VOXB + j] = inz[(size_t)(ci0 + u) * Vi + sp[j]];
#pragma unroll
            for (int u = 0; u < UNR; ++u) {
                const float* wp = wrow + (ci0 + u) * COB;
#pragma unroll
                for (int co = 0; co < COB; ++co) {
                    const float wgt = wp[co];
#pragma unroll
                    for (int j = 0; j < VOXB; ++j)
                        acc[co * VOXB + j] = fmaf(xv[u * VOXB + j], wgt, acc[co * VOXB + j]);
                }
            }
        }
    }
#pragma unroll
    for (int co = 0; co < COB; ++co)
#pragma unroll
        for (int j = 0; j < VOXB; ++j)
            part[((size_t)z * Cout + co0 + co) * Vo + vbase + j * 256] = acc[co * VOXB + j];
}

// ---------------------------------------------------------------------------
// BN stats over split partials: for each (c, segment), sum over splits s of
// part[s][c][v], accumulating t and t^2. pstat[c][seg] = (sum, sumsq).
// ---------------------------------------------------------------------------
__global__ __launch_bounds__(256) void bn_stats_part_v2(const float* __restrict__ part,
                                                        float* __restrict__ pstat,
                                                        int C, int V, int S, int chunk) {
    const int c = blockIdx.x, seg = blockIdx.y;
    const size_t base = (size_t)c * V + (size_t)seg * chunk;
    float s1 = 0.f, s2 = 0.f;
    for (int i = threadIdx.x * 4; i < chunk; i += 1024) {
        float4 t = make_float4(0.f, 0.f, 0.f, 0.f);
        for (int s = 0; s < S; ++s) {
            const float4 v = *(const float4*)(part + (size_t)s * C * V + base + i);
            t.x += v.x; t.y += v.y; t.z += v.z; t.w += v.w;
        }
        s1 += t.x + t.y + t.z + t.w;
        s2 = fmaf(t.x, t.x, fmaf(t.y, t.y, fmaf(t.z, t.z, fmaf(t.w, t.w, s2))));
    }
#pragma unroll
    for (int off = 32; off > 0; off >>= 1) {
        s1 += __shfl_down(s1, off, 64);
        s2 += __shfl_down(s2, off, 64);
    }
    __shared__ float sh[8];
    const int wid  = threadIdx.x >> 6;
    const int lane = threadIdx.x & 63;
    if (lane == 0) { sh[wid] = s1; sh[4 + wid] = s2; }
    __syncthreads();
    if (threadIdx.x == 0) {
        pstat[(c * gridDim.y + seg) * 2]     = sh[0] + sh[1] + sh[2] + sh[3];
        pstat[(c * gridDim.y + seg) * 2 + 1] = sh[4] + sh[5] + sh[6] + sh[7];
    }
}

__global__ __launch_bounds__(64) void bn_stats_final(const float* __restrict__ pstat,
                                                     float* __restrict__ stats,
                                                     int S, int V) {
    const int c = blockIdx.x;
    float s1 = 0.f, s2 = 0.f;
    if ((int)threadIdx.x < S) {
        s1 = pstat[(c * S + threadIdx.x) * 2];
        s2 = pstat[(c * S + threadIdx.x) * 2 + 1];
    }
#pragma unroll
    for (int off = 32; off > 0; off >>= 1) {
        s1 += __shfl_down(s1, off, 64);
        s2 += __shfl_down(s2, off, 64);
    }
    if (threadIdx.x == 0) {
        const float inv  = 1.f / (float)V;
        const float mean = s1 * inv;
        const float var  = s2 * inv - mean * mean;
        stats[2 * c]     = mean;
        stats[2 * c + 1] = rsqrtf(var + EPS);
    }
}

// ---------------------------------------------------------------------------
// split-reduce + BN normalize + LeakyReLU: dst = lrelu((sum_s part[s] - m) * rstd)
// ---------------------------------------------------------------------------
__global__ __launch_bounds__(256) void bn_apply_v3(const float* __restrict__ part,
                                                   float* __restrict__ dst,
                                                   const float* __restrict__ stats,
                                                   int C, int V4, int S, int total4) {
    const int idx = blockIdx.x * blockDim.x + threadIdx.x;
    if (idx >= total4) return;
    const int c = idx / V4;
    const int v = idx - c * V4;
    const float4* p4 = (const float4*)part;
    float4 t = make_float4(0.f, 0.f, 0.f, 0.f);
    for (int s = 0; s < S; ++s) {
        const float4 x = p4[(size_t)(s * C + c) * V4 + v];
        t.x += x.x; t.y += x.y; t.z += x.z; t.w += x.w;
    }
    const float mean = stats[2 * c];
    const float rstd = stats[2 * c + 1];
    float u;
    u = (t.x - mean) * rstd; t.x = u >= 0.f ? u : SLOPE * u;
    u = (t.y - mean) * rstd; t.y = u >= 0.f ? u : SLOPE * u;
    u = (t.z - mean) * rstd; t.z = u >= 0.f ? u : SLOPE * u;
    u = (t.w - mean) * rstd; t.w = u >= 0.f ? u : SLOPE * u;
    ((float4*)dst)[idx] = t;
}

// ---------------------------------------------------------------------------
// 2x2x2 maxpool stride 2
// ---------------------------------------------------------------------------
__global__ __launch_bounds__(256) void maxpool_kernel(const float* __restrict__ in,
                                                      float* __restrict__ out,
                                                      int D, int H, int W, int total) {
    const int Do = D >> 1, Ho = H >> 1, Wo = W >> 1;
    const int Vo = Do * Ho * Wo;
    const int idx = blockIdx.x * blockDim.x + threadIdx.x;
    if (idx >= total) return;
    const int c  = idx / Vo;
    const int v  = idx - c * Vo;
    const int ow = v % Wo;
    const int oh = (v / Wo) % Ho;
    const int od = v / (Wo * Ho);
    const size_t HW = (size_t)H * W;
    const float* p = in + (size_t)c * D * HW + (size_t)(2 * od) * HW + (size_t)(2 * oh) * W + 2 * ow;
    float m = p[0];
    m = fmaxf(m, p[1]);
    m = fmaxf(m, p[W]);
    m = fmaxf(m, p[W + 1]);
    m = fmaxf(m, p[HW]);
    m = fmaxf(m, p[HW + 1]);
    m = fmaxf(m, p[HW + W]);
    m = fmaxf(m, p[HW + W + 1]);
    out[idx] = m;
}

// ---------------------------------------------------------------------------
// final 1x1x1 conv + bias, float4
// ---------------------------------------------------------------------------
__global__ __launch_bounds__(256) void final_v2(const float* __restrict__ in,
                                                const float* __restrict__ w,
                                                const float* __restrict__ b,
                                                float* __restrict__ out, int C, int V4) {
    const int idx = blockIdx.x * blockDim.x + threadIdx.x;
    if (idx >= V4) return;
    const float bb = b[0];
    float4 acc = make_float4(bb, bb, bb, bb);
    for (int c = 0; c < C; ++c) {
        const float4 v = ((const float4*)in)[(size_t)c * V4 + idx];
        const float wc = w[c];
        acc.x = fmaf(v.x, wc, acc.x);
        acc.y = fmaf(v.y, wc, acc.y);
        acc.z = fmaf(v.z, wc, acc.z);
        acc.w = fmaf(v.w, wc, acc.w);
    }
    ((float4*)out)[idx] = acc;
}

// ---------------------------------------------------------------------------

extern "C" void kernel_launch(void* const* d_in, const int* in_sizes, int n_in,
                              void* d_out, int out_size, void* d_ws, size_t ws_size,
                              hipStream_t stream) {
    const float* x      = (const float*)d_in[0];
    const float* wf1    = (const float*)d_in[1];
    const float* wf2    = (const float*)d_in[2];
    const float* wd1a   = (const float*)d_in[3];
    const float* wd1b   = (const float*)d_in[4];
    const float* wd2a   = (const float*)d_in[5];
    const float* wd2b   = (const float*)d_in[6];
    const float* wd3a   = (const float*)d_in[7];
    const float* wd3b   = (const float*)d_in[8];
    const float* wt1    = (const float*)d_in[9];
    const float* wu1a   = (const float*)d_in[10];
    const float* wu1b   = (const float*)d_in[11];
    const float* wt2    = (const float*)d_in[12];
    const float* wu2a   = (const float*)d_in[13];
    const float* wu2b   = (const float*)d_in[14];
    const float* wt3    = (const float*)d_in[15];
    const float* wu3a   = (const float*)d_in[16];
    const float* wu3b   = (const float*)d_in[17];
    const float* w_fin  = (const float*)d_in[18];
    const float* b_fin  = (const float*)d_in[19];
    float* out = (float*)d_out;

    const int V0 = 64 * 64 * 64;
    const int V1 = 32 * 32 * 32;
    const int V2 = 16 * 16 * 16;
    const int V3 = 8 * 8 * 8;

    float* ws    = (float*)d_ws;
    float* cat3  = ws;                         // 32 * V0   (x1 | up3)
    float* cat2  = cat3 + (size_t)32 * V0;     // 64 * V1   (x2 | up2)
    float* cat1  = cat2 + (size_t)64 * V1;     // 128 * V2  (x3 | up1)
    float* x4    = cat1 + (size_t)128 * V2;    // 128 * V3
    float* tA    = x4   + (size_t)128 * V3;    // 16 * V0
    float* tB    = tA   + (size_t)16 * V0;     // 16 * V0
    float* part  = tB   + (size_t)16 * V0;     // 16 * V0 (max split-partial buffer)
    float* stats = part + (size_t)16 * V0;     // 256
    float* pstat = stats + 256;                // 128*16*2 = 4096

    auto blocks = [](int n) { return (n + 255) / 256; };

    auto bn_lrelu = [&](const float* p, float* dstp, int C, int V, int S) {
        const int NSEG = (V >= V0) ? 16 : (V == V1) ? 8 : (V == V2) ? 2 : 1;
        hipLaunchKernelGGL(bn_stats_part_v2, dim3(C, NSEG), dim3(256), 0, stream,
                           p, pstat, C, V, S, V / NSEG);
        hipLaunchKernelGGL(bn_stats_final, dim3(C), dim3(64), 0, stream, pstat, stats, NSEG, V);
        const int total4 = C * V / 4;
        hipLaunchKernelGGL(bn_apply_v3, dim3(blocks(total4)), dim3(256), 0, stream,
                           p, dstp, stats, C, V / 4, S, total4);
    };
    auto maxpool = [&](const float* in, float* o, int C, int D, int H, int W) {
        const int total = C * (D / 2) * (H / 2) * (W / 2);
        hipLaunchKernelGGL(maxpool_kernel, dim3(blocks(total)), dim3(256), 0, stream,
                           in, o, D, H, W, total);
    };

#define CONV(CIN, CC, COB, VOXB, in_, wt_, dst_, Cout, D_, H_, W_)                          \
    {                                                                                       \
        const int V_ = (D_) * (H_) * (W_);                                                  \
        const int CS = (CIN) / (CC);                                                        \
        dim3 g(V_ / (256 * (VOXB)), (Cout) / (COB), CS);                                    \
        hipLaunchKernelGGL((conv3_v4<CIN, CC, COB, VOXB>), g, dim3(256), 0, stream,         \
                           in_, wt_, part, D_, H_, W_);                                     \
        bn_lrelu(part, dst_, Cout, V_, CS);                                                 \
    }
#define UPCONV(CIN, CC, COB, VOXB, in_, wt_, dst_, Cout, Di_, Hi_, Wi_)                     \
    {                                                                                       \
        const int Vo_ = 8 * (Di_) * (Hi_) * (Wi_);                                          \
        const int CS = (CIN) / (CC);                                                        \
        dim3 g(Vo_ / (256 * (VOXB)), (Cout) / (COB), CS);                                   \
        hipLaunchKernelGGL((upconv_v4<CIN, CC, COB, VOXB>), g, dim3(256), 0, stream,        \
                           in_, wt_, part, Di_, Hi_, Wi_);                                  \
        bn_lrelu(part, dst_, Cout, Vo_, CS);                                                \
    }

    // ----- encoder -----
    CONV(1,   1,  8, 2, x,    wf1,  tA,   16, 64, 64, 64);   // 1024 blocks
    CONV(16,  16, 8, 2, tA,   wf2,  cat3, 16, 64, 64, 64);   // 1024
    maxpool(cat3, tA, 16, 64, 64, 64);
    CONV(16,  8,  8, 2, tA,   wd1a, tB,   32, 32, 32, 32);   // 512
    CONV(32,  8,  8, 2, tB,   wd1b, cat2, 32, 32, 32, 32);   // 1024
    maxpool(cat2, tA, 32, 32, 32, 32);
    CONV(32,  8,  8, 1, tA,   wd2a, tB,   64, 16, 16, 16);   // 512
    CONV(64,  8,  8, 1, tB,   wd2b, cat1, 64, 16, 16, 16);   // 1024
    maxpool(cat1, tA, 64, 16, 16, 16);
    CONV(64,  8,  8, 1, tA,   wd3a, tB,  128, 8, 8, 8);      // 256
    CONV(128, 8,  8, 1, tB,   wd3b, x4,  128, 8, 8, 8);      // 512

    // ----- decoder -----
    UPCONV(128, 16, 8, 1, x4, wt1, cat1 + (size_t)64 * V2, 64, 8, 8, 8);     // 1024
    CONV(128, 8,  8, 1, cat1, wu1a, tA,  64, 16, 16, 16);    // 2048
    CONV(64,  8,  8, 1, tA,   wu1b, tB,  64, 16, 16, 16);    // 1024

    UPCONV(64, 16, 8, 2, tB, wt2, cat2 + (size_t)32 * V1, 32, 16, 16, 16);   // 1024
    CONV(64,  16, 8, 2, cat2, wu2a, tA,  32, 32, 32, 32);    // 1024
    CONV(32,  8,  8, 2, tA,   wu2b, tB,  32, 32, 32, 32);    // 1024

    UPCONV(32, 32, 8, 2, tB, wt3, cat3 + (size_t)16 * V0, 16, 32, 32, 32);   // 1024
    CONV(32,  32, 8, 2, cat3, wu3a, tA,  16, 64, 64, 64);    // 1024
    CONV(16,  16, 8, 2, tA,   wu3b, tB,  16, 64, 64, 64);    // 1024

    // ----- final 1x1x1 conv + bias -----
    hipLaunchKernelGGL(final_v2, dim3(blocks(V0 / 4)), dim3(256), 0, stream,
                       tB, w_fin, b_fin, out, 16, V0 / 4);

#undef CONV
#undef UPCONV
}

// Round 4
// 22048.824 us; speedup vs baseline: 1.1784x; 1.1784x over previous
//
#include <hip/hip_runtime.h>

#define EPS   1e-5f
#define SLOPE 0.01f

// ---------------------------------------------------------------------------
// conv 3x3x3 pad=1 (cross-correlation), cout-register-blocked + optional ci-split.
// in: [CIN][D][H][W], wt: [Cout][CIN][3][3][3]
// grid: (V/(256*VOXB), Cout/COB, CIN/CC). Partials to part[z][co][v].
// UNR hard-capped at 4 to keep VGPR < 128 (R3 lesson: UNR=16 -> 256 VGPR + spills).
// ---------------------------------------------------------------------------
template <int CIN, int CC, int COB, int VOXB>
__global__ __launch_bounds__(256) void conv3_v5(const float* __restrict__ in,
                                                const float* __restrict__ wt,
                                                float* __restrict__ part,
                                                int D, int H, int W) {
    const int V    = D * H * W;
    const int Cout = gridDim.y * COB;
    const int z    = blockIdx.z;
    const int cib  = z * CC;
    __shared__ float wlds[27 * CC * COB];
    const int co0 = blockIdx.y * COB;
    for (int i = threadIdx.x; i < 27 * CC * COB; i += 256) {
        const int tap = i / (CC * COB);
        const int r   = i - tap * (CC * COB);
        const int ci  = r / COB;
        const int co  = r - ci * COB;
        wlds[i] = wt[((size_t)(co0 + co) * CIN + cib + ci) * 27 + tap];
    }
    __syncthreads();

    const float* inz = in + (size_t)cib * V;
    const int vbase = blockIdx.x * (256 * VOXB) + threadIdx.x;
    int dd[VOXB], hh[VOXB], ww[VOXB];
#pragma unroll
    for (int j = 0; j < VOXB; ++j) {
        const int v = vbase + j * 256;
        ww[j] = v % W;
        hh[j] = (v / W) % H;
        dd[j] = v / (W * H);
    }
    float acc[COB * VOXB];
#pragma unroll
    for (int i = 0; i < COB * VOXB; ++i) acc[i] = 0.f;

    constexpr int UNR = (CC < 4) ? CC : 4;   // <= 8 loads in flight, xv[<=8]

#pragma unroll
    for (int kd = 0; kd < 3; ++kd)
#pragma unroll
    for (int kh = 0; kh < 3; ++kh)
#pragma unroll
    for (int kw = 0; kw < 3; ++kw) {
        const int tap = (kd * 3 + kh) * 3 + kw;
        int sp[VOXB]; bool ok[VOXB];
#pragma unroll
        for (int j = 0; j < VOXB; ++j) {
            const int zd = dd[j] + kd - 1, zh = hh[j] + kh - 1, zw = ww[j] + kw - 1;
            ok[j] = ((unsigned)zd < (unsigned)D) & ((unsigned)zh < (unsigned)H) &
                    ((unsigned)zw < (unsigned)W);
            sp[j] = (zd * H + zh) * W + zw;
        }
        const float* wrow = &wlds[tap * CC * COB];
        for (int ci0 = 0; ci0 < CC; ci0 += UNR) {
            float xv[UNR * VOXB];
#pragma unroll
            for (int u = 0; u < UNR; ++u)
#pragma unroll
                for (int j = 0; j < VOXB; ++j)
                    xv[u * VOXB + j] = ok[j] ? inz[(size_t)(ci0 + u) * V + sp[j]] : 0.f;
#pragma unroll
            for (int u = 0; u < UNR; ++u) {
                const float* wp = wrow + (ci0 + u) * COB;
#pragma unroll
                for (int co = 0; co < COB; ++co) {
                    const float wgt = wp[co];
#pragma unroll
                    for (int j = 0; j < VOXB; ++j)
                        acc[co * VOXB + j] = fmaf(xv[u * VOXB + j], wgt, acc[co * VOXB + j]);
                }
            }
        }
    }
#pragma unroll
    for (int co = 0; co < COB; ++co)
#pragma unroll
        for (int j = 0; j < VOXB; ++j)
            part[((size_t)z * Cout + co0 + co) * V + vbase + j * 256] = acc[co * VOXB + j];
}

// ---------------------------------------------------------------------------
// upconv (NN-upsample x2 + circular 2x2x2 true convolution), cout-blocked + ci-split
// ---------------------------------------------------------------------------
template <int CIN, int CC, int COB, int VOXB>
__global__ __launch_bounds__(256) void upconv_v5(const float* __restrict__ in,
                                                 const float* __restrict__ wt,
                                                 float* __restrict__ part,
                                                 int Di, int Hi, int Wi) {
    const int Do = 2 * Di, Ho = 2 * Hi, Wo = 2 * Wi;
    const int Vo = Do * Ho * Wo;
    const int Vi = Di * Hi * Wi;
    const int Cout = gridDim.y * COB;
    const int z   = blockIdx.z;
    const int cib = z * CC;
    __shared__ float wlds[8 * CC * COB];
    const int co0 = blockIdx.y * COB;
    for (int i = threadIdx.x; i < 8 * CC * COB; i += 256) {
        const int tap = i / (CC * COB);
        const int r   = i - tap * (CC * COB);
        const int ci  = r / COB;
        const int co  = r - ci * COB;
        wlds[i] = wt[((size_t)(co0 + co) * CIN + cib + ci) * 8 + tap];
    }
    __syncthreads();

    const float* inz = in + (size_t)cib * Vi;
    const int vbase = blockIdx.x * (256 * VOXB) + threadIdx.x;
    int od[VOXB], oh[VOXB], ow[VOXB];
#pragma unroll
    for (int j = 0; j < VOXB; ++j) {
        const int v = vbase + j * 256;
        ow[j] = v % Wo;
        oh[j] = (v / Wo) % Ho;
        od[j] = v / (Wo * Ho);
    }
    float acc[COB * VOXB];
#pragma unroll
    for (int i = 0; i < COB * VOXB; ++i) acc[i] = 0.f;

    constexpr int UNR = (CC < 4) ? CC : 4;

#pragma unroll
    for (int kd = 0; kd < 2; ++kd)
#pragma unroll
    for (int kh = 0; kh < 2; ++kh)
#pragma unroll
    for (int kw = 0; kw < 2; ++kw) {
        const int tap = (kd * 2 + kh) * 2 + kw;
        int sp[VOXB];
#pragma unroll
        for (int j = 0; j < VOXB; ++j) {
            const int id = ((od[j] - kd + Do) & (Do - 1)) >> 1;
            const int ih = ((oh[j] - kh + Ho) & (Ho - 1)) >> 1;
            const int iw = ((ow[j] - kw + Wo) & (Wo - 1)) >> 1;
            sp[j] = (id * Hi + ih) * Wi + iw;
        }
        const float* wrow = &wlds[tap * CC * COB];
        for (int ci0 = 0; ci0 < CC; ci0 += UNR) {
            float xv[UNR * VOXB];
#pragma unroll
            for (int u = 0; u < UNR; ++u)
#pragma unroll
                for (int j = 0; j < VOXB; ++j)
                    xv[u * VOXB + j] = inz[(size_t)(ci0 + u) * Vi + sp[j]];
#pragma unroll
            for (int u = 0; u < UNR; ++u) {
                const float* wp = wrow + (ci0 + u) * COB;
#pragma unroll
                for (int co = 0; co < COB; ++co) {
                    const float wgt = wp[co];
#pragma unroll
                    for (int j = 0; j < VOXB; ++j)
                        acc[co * VOXB + j] = fmaf(xv[u * VOXB + j], wgt, acc[co * VOXB + j]);
                }
            }
        }
    }
#pragma unroll
    for (int co = 0; co < COB; ++co)
#pragma unroll
        for (int j = 0; j < VOXB; ++j)
            part[((size_t)z * Cout + co0 + co) * Vo + vbase + j * 256] = acc[co * VOXB + j];
}

// ---------------------------------------------------------------------------
// BN stats over split partials. pstat[c][seg] = (sum, sumsq) of sum_s part[s][c][.]
// ---------------------------------------------------------------------------
__global__ __launch_bounds__(256) void bn_stats_part_v2(const float* __restrict__ part,
                                                        float* __restrict__ pstat,
                                                        int C, int V, int S, int chunk) {
    const int c = blockIdx.x, seg = blockIdx.y;
    const size_t base = (size_t)c * V + (size_t)seg * chunk;
    float s1 = 0.f, s2 = 0.f;
    for (int i = threadIdx.x * 4; i < chunk; i += 1024) {
        float4 t = make_float4(0.f, 0.f, 0.f, 0.f);
        for (int s = 0; s < S; ++s) {
            const float4 v = *(const float4*)(part + (size_t)s * C * V + base + i);
            t.x += v.x; t.y += v.y; t.z += v.z; t.w += v.w;
        }
        s1 += t.x + t.y + t.z + t.w;
        s2 = fmaf(t.x, t.x, fmaf(t.y, t.y, fmaf(t.z, t.z, fmaf(t.w, t.w, s2))));
    }
#pragma unroll
    for (int off = 32; off > 0; off >>= 1) {
        s1 += __shfl_down(s1, off, 64);
        s2 += __shfl_down(s2, off, 64);
    }
    __shared__ float sh[8];
    const int wid  = threadIdx.x >> 6;
    const int lane = threadIdx.x & 63;
    if (lane == 0) { sh[wid] = s1; sh[4 + wid] = s2; }
    __syncthreads();
    if (threadIdx.x == 0) {
        pstat[(c * gridDim.y + seg) * 2]     = sh[0] + sh[1] + sh[2] + sh[3];
        pstat[(c * gridDim.y + seg) * 2 + 1] = sh[4] + sh[5] + sh[6] + sh[7];
    }
}

__global__ __launch_bounds__(64) void bn_stats_final(const float* __restrict__ pstat,
                                                     float* __restrict__ stats,
                                                     int S, int V) {
    const int c = blockIdx.x;
    float s1 = 0.f, s2 = 0.f;
    if ((int)threadIdx.x < S) {
        s1 = pstat[(c * S + threadIdx.x) * 2];
        s2 = pstat[(c * S + threadIdx.x) * 2 + 1];
    }
#pragma unroll
    for (int off = 32; off > 0; off >>= 1) {
        s1 += __shfl_down(s1, off, 64);
        s2 += __shfl_down(s2, off, 64);
    }
    if (threadIdx.x == 0) {
        const float inv  = 1.f / (float)V;
        const float mean = s1 * inv;
        const float var  = s2 * inv - mean * mean;
        stats[2 * c]     = mean;
        stats[2 * c + 1] = rsqrtf(var + EPS);
    }
}

// ---------------------------------------------------------------------------
// split-reduce + BN normalize + LeakyReLU: dst = lrelu((sum_s part[s] - m) * rstd)
// ---------------------------------------------------------------------------
__global__ __launch_bounds__(256) void bn_apply_v3(const float* __restrict__ part,
                                                   float* __restrict__ dst,
                                                   const float* __restrict__ stats,
                                                   int C, int V4, int S, int total4) {
    const int idx = blockIdx.x * blockDim.x + threadIdx.x;
    if (idx >= total4) return;
    const int c = idx / V4;
    const int v = idx - c * V4;
    const float4* p4 = (const float4*)part;
    float4 t = make_float4(0.f, 0.f, 0.f, 0.f);
    for (int s = 0; s < S; ++s) {
        const float4 x = p4[(size_t)(s * C + c) * V4 + v];
        t.x += x.x; t.y += x.y; t.z += x.z; t.w += x.w;
    }
    const float mean = stats[2 * c];
    const float rstd = stats[2 * c + 1];
    float u;
    u = (t.x - mean) * rstd; t.x = u >= 0.f ? u : SLOPE * u;
    u = (t.y - mean) * rstd; t.y = u >= 0.f ? u : SLOPE * u;
    u = (t.z - mean) * rstd; t.z = u >= 0.f ? u : SLOPE * u;
    u = (t.w - mean) * rstd; t.w = u >= 0.f ? u : SLOPE * u;
    ((float4*)dst)[idx] = t;
}

// ---------------------------------------------------------------------------
// 2x2x2 maxpool stride 2
// ---------------------------------------------------------------------------
__global__ __launch_bounds__(256) void maxpool_kernel(const float* __restrict__ in,
                                                      float* __restrict__ out,
                                                      int D, int H, int W, int total) {
    const int Do = D >> 1, Ho = H >> 1, Wo = W >> 1;
    const int Vo = Do * Ho * Wo;
    const int idx = blockIdx.x * blockDim.x + threadIdx.x;
    if (idx >= total) return;
    const int c  = idx / Vo;
    const int v  = idx - c * Vo;
    const int ow = v % Wo;
    const int oh = (v / Wo) % Ho;
    const int od = v / (Wo * Ho);
    const size_t HW = (size_t)H * W;
    const float* p = in + (size_t)c * D * HW + (size_t)(2 * od) * HW + (size_t)(2 * oh) * W + 2 * ow;
    float m = p[0];
    m = fmaxf(m, p[1]);
    m = fmaxf(m, p[W]);
    m = fmaxf(m, p[W + 1]);
    m = fmaxf(m, p[HW]);
    m = fmaxf(m, p[HW + 1]);
    m = fmaxf(m, p[HW + W]);
    m = fmaxf(m, p[HW + W + 1]);
    out[idx] = m;
}

// ---------------------------------------------------------------------------
// final 1x1x1 conv + bias, float4
// ---------------------------------------------------------------------------
__global__ __launch_bounds__(256) void final_v2(const float* __restrict__ in,
                                                const float* __restrict__ w,
                                                const float* __restrict__ b,
                                                float* __restrict__ out, int C, int V4) {
    const int idx = blockIdx.x * blockDim.x + threadIdx.x;
    if (idx >= V4) return;
    const float bb = b[0];
    float4 acc = make_float4(bb, bb, bb, bb);
    for (int c = 0; c < C; ++c) {
        const float4 v = ((const float4*)in)[(size_t)c * V4 + idx];
        const float wc = w[c];
        acc.x = fmaf(v.x, wc, acc.x);
        acc.y = fmaf(v.y, wc, acc.y);
        acc.z = fmaf(v.z, wc, acc.z);
        acc.w = fmaf(v.w, wc, acc.w);
    }
    ((float4*)out)[idx] = acc;
}

// ---------------------------------------------------------------------------

extern "C" void kernel_launch(void* const* d_in, const int* in_sizes, int n_in,
                              void* d_out, int out_size, void* d_ws, size_t ws_size,
                              hipStream_t stream) {
    const float* x      = (const float*)d_in[0];
    const float* wf1    = (const float*)d_in[1];
    const float* wf2    = (const float*)d_in[2];
    const float* wd1a   = (const float*)d_in[3];
    const float* wd1b   = (const float*)d_in[4];
    const float* wd2a   = (const float*)d_in[5];
    const float* wd2b   = (const float*)d_in[6];
    const float* wd3a   = (const float*)d_in[7];
    const float* wd3b   = (const float*)d_in[8];
    const float* wt1    = (const float*)d_in[9];
    const float* wu1a   = (const float*)d_in[10];
    const float* wu1b   = (const float*)d_in[11];
    const float* wt2    = (const float*)d_in[12];
    const float* wu2a   = (const float*)d_in[13];
    const float* wu2b   = (const float*)d_in[14];
    const float* wt3    = (const float*)d_in[15];
    const float* wu3a   = (const float*)d_in[16];
    const float* wu3b   = (const float*)d_in[17];
    const float* w_fin  = (const float*)d_in[18];
    const float* b_fin  = (const float*)d_in[19];
    float* out = (float*)d_out;

    const int V0 = 64 * 64 * 64;
    const int V1 = 32 * 32 * 32;
    const int V2 = 16 * 16 * 16;
    const int V3 = 8 * 8 * 8;

    float* ws    = (float*)d_ws;
    float* cat3  = ws;                         // 32 * V0
    float* cat2  = cat3 + (size_t)32 * V0;     // 64 * V1
    float* cat1  = cat2 + (size_t)64 * V1;     // 128 * V2
    float* x4    = cat1 + (size_t)128 * V2;    // 128 * V3
    float* tA    = x4   + (size_t)128 * V3;    // 16 * V0
    float* tB    = tA   + (size_t)16 * V0;     // 16 * V0
    float* part  = tB   + (size_t)16 * V0;     // 16 * V0 (max S*Cout*V over all layers)
    float* stats = part + (size_t)16 * V0;     // 256
    float* pstat = stats + 256;                // 128*16*2

    auto blocks = [](int n) { return (n + 255) / 256; };

    auto bn_lrelu = [&](const float* p, float* dstp, int C, int V, int S) {
        const int NSEG = (V >= V0) ? 16 : (V == V1) ? 8 : (V == V2) ? 2 : 1;
        hipLaunchKernelGGL(bn_stats_part_v2, dim3(C, NSEG), dim3(256), 0, stream,
                           p, pstat, C, V, S, V / NSEG);
        hipLaunchKernelGGL(bn_stats_final, dim3(C), dim3(64), 0, stream, pstat, stats, NSEG, V);
        const int total4 = C * V / 4;
        hipLaunchKernelGGL(bn_apply_v3, dim3(blocks(total4)), dim3(256), 0, stream,
                           p, dstp, stats, C, V / 4, S, total4);
    };
    auto maxpool = [&](const float* in, float* o, int C, int D, int H, int W) {
        const int total = C * (D / 2) * (H / 2) * (W / 2);
        hipLaunchKernelGGL(maxpool_kernel, dim3(blocks(total)), dim3(256), 0, stream,
                           in, o, D, H, W, total);
    };

#define CONV(CIN, CC, COB, VOXB, in_, wt_, dst_, Cout, D_, H_, W_)                          \
    {                                                                                       \
        const int V_ = (D_) * (H_) * (W_);                                                  \
        const int CS = (CIN) / (CC);                                                        \
        dim3 g(V_ / (256 * (VOXB)), (Cout) / (COB), CS);                                    \
        hipLaunchKernelGGL((conv3_v5<CIN, CC, COB, VOXB>), g, dim3(256), 0, stream,         \
                           in_, wt_, part, D_, H_, W_);                                     \
        bn_lrelu(part, dst_, Cout, V_, CS);                                                 \
    }
#define UPCONV(CIN, CC, COB, VOXB, in_, wt_, dst_, Cout, Di_, Hi_, Wi_)                     \
    {                                                                                       \
        const int Vo_ = 8 * (Di_) * (Hi_) * (Wi_);                                          \
        const int CS = (CIN) / (CC);                                                        \
        dim3 g(Vo_ / (256 * (VOXB)), (Cout) / (COB), CS);                                   \
        hipLaunchKernelGGL((upconv_v5<CIN, CC, COB, VOXB>), g, dim3(256), 0, stream,        \
                           in_, wt_, part, Di_, Hi_, Wi_);                                  \
        bn_lrelu(part, dst_, Cout, Vo_, CS);                                                \
    }

    // ----- encoder -----                                   blocks
    CONV(1,   1,  8, 2, x,    wf1,  tA,   16, 64, 64, 64);   // (512,2,1)=1024
    CONV(16,  16, 8, 2, tA,   wf2,  cat3, 16, 64, 64, 64);   // (512,2,1)=1024
    maxpool(cat3, tA, 16, 64, 64, 64);
    CONV(16,  16, 8, 1, tA,   wd1a, tB,   32, 32, 32, 32);   // (128,4,1)=512
    CONV(32,  16, 8, 1, tB,   wd1b, cat2, 32, 32, 32, 32);   // (128,4,2)=1024
    maxpool(cat2, tA, 32, 32, 32, 32);
    CONV(32,  8,  4, 1, tA,   wd2a, tB,   64, 16, 16, 16);   // (16,16,4)=1024
    CONV(64,  8,  4, 1, tB,   wd2b, cat1, 64, 16, 16, 16);   // (16,16,8)=2048
    maxpool(cat1, tA, 64, 16, 16, 16);
    CONV(64,  8,  4, 1, tA,   wd3a, tB,  128, 8, 8, 8);      // (2,32,8)=512
    CONV(128, 8,  4, 1, tB,   wd3b, x4,  128, 8, 8, 8);      // (2,32,16)=1024

    // ----- decoder -----
    UPCONV(128, 16, 4, 1, x4, wt1, cat1 + (size_t)64 * V2, 64, 8, 8, 8);     // (16,16,8)=2048
    CONV(128, 8,  4, 1, cat1, wu1a, tA,  64, 16, 16, 16);    // (16,16,16)=4096
    CONV(64,  8,  4, 1, tA,   wu1b, tB,  64, 16, 16, 16);    // (16,16,8)=2048

    UPCONV(64, 16, 8, 1, tB, wt2, cat2 + (size_t)32 * V1, 32, 16, 16, 16);   // (128,4,4)=2048
    CONV(64,  16, 8, 1, cat2, wu2a, tA,  32, 32, 32, 32);    // (128,4,4)=2048
    CONV(32,  16, 8, 1, tA,   wu2b, tB,  32, 32, 32, 32);    // (128,4,2)=1024

    UPCONV(32, 32, 8, 2, tB, wt3, cat3 + (size_t)16 * V0, 16, 32, 32, 32);   // (512,2,1)=1024
    CONV(32,  32, 8, 2, cat3, wu3a, tA,  16, 64, 64, 64);    // (512,2,1)=1024
    CONV(16,  16, 8, 2, tA,   wu3b, tB,  16, 64, 64, 64);    // (512,2,1)=1024

    // ----- final 1x1x1 conv + bias -----
    hipLaunchKernelGGL(final_v2, dim3(blocks(V0 / 4)), dim3(256), 0, stream,
                       tB, w_fin, b_fin, out, 16, V0 / 4);

#undef CONV
#undef UPCONV
}